// Round 3
// baseline (38453.555 us; speedup 1.0000x reference)
//
#include <hip/hip_runtime.h>
#include <hip/hip_bf16.h>

#define TSTEPS 4096
#define XD 256
#define HD 2048
#define YD 256
#define KD 2304   // XD + HD
#define NWG 256
#define NT 512

// ---- LDS layout (bytes) ----
#define WU_OFF 0
#define WR_OFF (8*KD*2)            // 36864
#define WC_OFF (16*KD*2)           // 73728
#define WY_OFF (24*KD*2)           // 110592
#define V1_OFF (WY_OFF + HD*4)     // 118784  v1 = [x_t | h_{t-1}]
#define V2_OFF (V1_OFF + KD*4)     // 128000  v2 = [x_t | r]
#define RED_OFF (V2_OFF + KD*4)    // 137216  red: u[8], yp[8], bu[8], br[8], bc[8], by
#define LDS_BYTES (RED_OFF + 256)  // 137472

// ---- workspace: double-buffered h and r exchange, sentinel-armed ----
// |h|<=1 and |r|<=1 provably (tanh/sigmoid bounds, h0=0), so 0x7F7F7F7F
// (3.39e38) can never be produced -> safe sentinel, settable via memset(0x7F).
#define HB0_OFF 0
#define HB1_OFF 8192
#define RB0_OFF 16384
#define RB1_OFF 24576
#define WS_INIT_BYTES 32768
#define SENT32 0x7F7F7F7Fu

__device__ __forceinline__ float bflo(unsigned u){ return __uint_as_float(u << 16); }
__device__ __forceinline__ float bfhi(unsigned u){ return __uint_as_float(u & 0xffff0000u); }
__device__ __forceinline__ unsigned short f2bf(float f){
  unsigned b = __float_as_uint(f);
  b += 0x7fffu + ((b >> 16) & 1u);   // RTNE (inputs finite)
  return (unsigned short)(b >> 16);
}
__device__ __forceinline__ float sigmoidf_(float x){ return 1.0f / (1.0f + __expf(-x)); }

__device__ __forceinline__ void gst32f(float* p, float v){
  __hip_atomic_store(p, v, __ATOMIC_RELAXED, __HIP_MEMORY_SCOPE_AGENT);
}

// Poll-gather 2048 floats (8KB) from a sentinel-armed exchange buffer into LDS.
// Each of 512 threads owns 16B. Agent-scope relaxed loads bypass L1/L2 -> MALL
// is the coherence point (mechanism validated by R2's correctness).
__device__ __forceinline__ void gather2048(const float* gbuf, float* lds, int tid, long* budget){
  const unsigned long long* p = (const unsigned long long*)gbuf + 2*tid;
  unsigned long long a, b;
  for (;;) {
    a = __hip_atomic_load(p,     __ATOMIC_RELAXED, __HIP_MEMORY_SCOPE_AGENT);
    b = __hip_atomic_load(p + 1, __ATOMIC_RELAXED, __HIP_MEMORY_SCOPE_AGENT);
    if (((unsigned)a != SENT32) & ((unsigned)(a>>32) != SENT32) &
        ((unsigned)b != SENT32) & ((unsigned)(b>>32) != SENT32)) break;
    if (--(*budget) < 0) break;   // anti-hang: accept stale rather than deadlock
  }
  ((unsigned long long*)lds)[2*tid]     = a;
  ((unsigned long long*)lds)[2*tid + 1] = b;
}

// Re-arm my 8-float slice (32B) of a consumed exchange buffer with sentinel.
__device__ __forceinline__ void reset_slice(float* gbuf, int col0, int tid){
  if (tid < 2) {
    unsigned long long s = 0x7F7F7F7F7F7F7F7FULL;
    unsigned long long* p = (unsigned long long*)(gbuf + col0) + 2*tid;
    __hip_atomic_store(p,     s, __ATOMIC_RELAXED, __HIP_MEMORY_SCOPE_AGENT);
    __hip_atomic_store(p + 1, s, __ATOMIC_RELAXED, __HIP_MEMORY_SCOPE_AGENT);
  }
}

extern "C" __global__ void __launch_bounds__(NT)
gru_persistent(const float* __restrict__ x,  const float* __restrict__ h0,
               const float* __restrict__ Wc, const float* __restrict__ Wu,
               const float* __restrict__ Wr, const float* __restrict__ bc,
               const float* __restrict__ bu, const float* __restrict__ br,
               const float* __restrict__ Wy, const float* __restrict__ by,
               float* __restrict__ out, unsigned* wsu)
{
  extern __shared__ char smem[];
  unsigned short* wuS = (unsigned short*)(smem + WU_OFF);
  unsigned short* wrS = (unsigned short*)(smem + WR_OFF);
  unsigned short* wcS = (unsigned short*)(smem + WC_OFF);
  float* wyS = (float*)(smem + WY_OFF);
  float* v1  = (float*)(smem + V1_OFF);
  float* v2  = (float*)(smem + V2_OFF);
  float* red = (float*)(smem + RED_OFF);

  float* hb[2] = { (float*)((char*)wsu + HB0_OFF), (float*)((char*)wsu + HB1_OFF) };
  float* rb[2] = { (float*)((char*)wsu + RB0_OFF), (float*)((char*)wsu + RB1_OFF) };

  const int wg = blockIdx.x, tid = threadIdx.x;
  const int col0 = 8 * wg;

  // ---- one-time weight staging: WG j owns gate cols [8j,8j+8), y col j ----
  for (int idx = tid; idx < 8*KD; idx += NT) {
    int c = idx & 7, k = idx >> 3;
    size_t g = (size_t)k * HD + col0 + c;   // W is [KD, 2048] row-major
    wuS[c*KD + k] = f2bf(Wu[g]);
    wrS[c*KD + k] = f2bf(Wr[g]);
    wcS[c*KD + k] = f2bf(Wc[g]);
  }
  for (int k = tid; k < HD; k += NT) wyS[k] = Wy[(size_t)k * YD + wg];
  if (tid < 8) {
    red[16+tid] = bu[col0+tid];
    red[24+tid] = br[col0+tid];
    red[32+tid] = bc[col0+tid];
  }
  if (tid == 0) red[40] = by[wg];
  __syncthreads();

  long budget = 20000000;   // poll-round cap (~2s worst case), then bail

  for (int t = 0; t < TSTEPS; ++t) {
    // x_t fill (independent; overlaps the h poll) ...
    if (tid < XD/4) {
      float4 xv = ((const float4*)(x + (size_t)t * XD))[tid];
      ((float4*)v1)[tid] = xv;
      ((float4*)v2)[tid] = xv;
    }
    // ... then h_{t-1}: data IS the barrier (poll until non-sentinel)
    if (t == 0) {
      ((float4*)(v1 + XD))[tid] = ((const float4*)h0)[tid];
    } else {
      gather2048(hb[(t+1)&1], v1 + XD, tid, &budget);
    }
    __syncthreads();
    // h_{t-1} complete => every WG published h_{t-1} => every WG consumed
    // r_{t-1} => safe to re-arm my slice of rb[(t-1)&1] (rewritten at t+1).
    if (t) reset_slice(rb[(t+1)&1], col0, tid);

    // ---- phase 1: Lu (half-waves 0-7), Lr (half-waves 8-15); K = 2304 ----
    {
      int hw = tid >> 5, l = tid & 31, c = hw & 7;
      const unsigned short* wcol = ((hw < 8) ? wuS : wrS) + c * KD;
      float4 acc = make_float4(0.f, 0.f, 0.f, 0.f);
      #pragma unroll
      for (int i = 0; i < KD/128; ++i) {       // 18 iters, 4 MACs each
        int k = 4 * (l + 32 * i);
        float4 vv = *(const float4*)(v1 + k);
        uint2  wq = *(const uint2*)(wcol + k);
        acc.x = fmaf(vv.x, bflo(wq.x), acc.x);
        acc.y = fmaf(vv.y, bfhi(wq.x), acc.y);
        acc.z = fmaf(vv.z, bflo(wq.y), acc.z);
        acc.w = fmaf(vv.w, bfhi(wq.y), acc.w);
      }
      float s = (acc.x + acc.y) + (acc.z + acc.w);
      s += __shfl_xor(s, 16); s += __shfl_xor(s, 8); s += __shfl_xor(s, 4);
      s += __shfl_xor(s, 2);  s += __shfl_xor(s, 1);
      if (l == 0) {
        if (hw < 8) red[c] = sigmoidf_(s + red[16+c]);                              // u gate
        else gst32f(rb[t&1] + col0 + c, sigmoidf_(s + red[24+c]) * v1[XD+col0+c]);  // r*h
      }
    }

    // r_t exchange: poll the data directly (fast waves gather while slow
    // waves still compute — no intra-WG sync needed before polling).
    gather2048(rb[t&1], v2 + XD, tid, &budget);
    __syncthreads();
    // r_t complete => every WG finished phase 1 => every WG consumed h_{t-1}
    // => safe to re-arm my slice of hb[(t-1)&1] (rewritten at t+1).
    if (t) reset_slice(hb[(t+1)&1], col0, tid);

    // ---- phase 2: candidate c (wave w -> col w) + y[t-1] partials ----
    {
      int w = tid >> 6, l6 = tid & 63;
      const unsigned short* ccol = wcS + w * KD;
      float4 acc = make_float4(0.f, 0.f, 0.f, 0.f);
      #pragma unroll
      for (int i = 0; i < KD/256; ++i) {       // 9 iters
        int k = 4 * (l6 + 64 * i);
        float4 vv = *(const float4*)(v2 + k);
        uint2  wq = *(const uint2*)(ccol + k);
        acc.x = fmaf(vv.x, bflo(wq.x), acc.x);
        acc.y = fmaf(vv.y, bfhi(wq.x), acc.y);
        acc.z = fmaf(vv.z, bflo(wq.y), acc.z);
        acc.w = fmaf(vv.w, bfhi(wq.y), acc.w);
      }
      float s = (acc.x + acc.y) + (acc.z + acc.w);
      s += __shfl_xor(s, 32); s += __shfl_xor(s, 16); s += __shfl_xor(s, 8);
      s += __shfl_xor(s, 4);  s += __shfl_xor(s, 2);  s += __shfl_xor(s, 1);

      // y[t-1] = h_{t-1} @ Wy[:,wg] : wave w covers k in [256w, 256w+256)
      int k = 256 * w + 4 * l6;
      float4 hv  = *(const float4*)(v1 + XD + k);
      float4 wy4 = *(const float4*)(wyS + k);
      float ys = fmaf(hv.x, wy4.x, fmaf(hv.y, wy4.y, fmaf(hv.z, wy4.z, hv.w * wy4.w)));
      ys += __shfl_xor(ys, 32); ys += __shfl_xor(ys, 16); ys += __shfl_xor(ys, 8);
      ys += __shfl_xor(ys, 4);  ys += __shfl_xor(ys, 2);  ys += __shfl_xor(ys, 1);

      if (l6 == 0) {
        red[8 + w] = ys;
        float cc = tanhf(s + red[32 + w]);
        float u  = red[w];
        float hp = v1[XD + col0 + w];
        gst32f(hb[t&1] + col0 + w, cc * u + hp * (1.0f - u));   // h_t slice
      }
    }
    __syncthreads();
    if (tid == 0 && t > 0) {
      float y = red[8]+red[9]+red[10]+red[11]+red[12]+red[13]+red[14]+red[15] + red[40];
      out[(size_t)(t-1) * YD + wg] = y;   // fire-and-forget; ack hides under next poll
    }
  }

  // ---- epilogue: y[T-1] and h_fin ----
  gather2048(hb[(TSTEPS-1)&1], v1 + XD, tid, &budget);
  __syncthreads();
  {
    int w = tid >> 6, l6 = tid & 63;
    int k = 256 * w + 4 * l6;
    float4 hv  = *(const float4*)(v1 + XD + k);
    float4 wy4 = *(const float4*)(wyS + k);
    float ys = fmaf(hv.x, wy4.x, fmaf(hv.y, wy4.y, fmaf(hv.z, wy4.z, hv.w * wy4.w)));
    ys += __shfl_xor(ys, 32); ys += __shfl_xor(ys, 16); ys += __shfl_xor(ys, 8);
    ys += __shfl_xor(ys, 4);  ys += __shfl_xor(ys, 2);  ys += __shfl_xor(ys, 1);
    if (l6 == 0) red[8 + w] = ys;
  }
  __syncthreads();
  if (tid == 0) {
    float y = red[8]+red[9]+red[10]+red[11]+red[12]+red[13]+red[14]+red[15] + red[40];
    out[(size_t)(TSTEPS-1) * YD + wg] = y;
  }
  if (tid < 8) out[(size_t)TSTEPS * YD + col0 + tid] = v1[XD + col0 + tid];
}

extern "C" void kernel_launch(void* const* d_in, const int* in_sizes, int n_in,
                              void* d_out, int out_size, void* d_ws, size_t ws_size,
                              hipStream_t stream) {
  const float* x  = (const float*)d_in[0];
  const float* h0 = (const float*)d_in[1];
  const float* Wc = (const float*)d_in[2];
  const float* Wu = (const float*)d_in[3];
  const float* Wr = (const float*)d_in[4];
  const float* bc = (const float*)d_in[5];
  const float* bu = (const float*)d_in[6];
  const float* br = (const float*)d_in[7];
  const float* Wy = (const float*)d_in[8];
  const float* by = (const float*)d_in[9];
  float* out = (float*)d_out;
  unsigned* wsu = (unsigned*)d_ws;

  // >64 KB dynamic LDS on gfx950 (160 KB/CU). Idempotent; capture-safe.
  hipFuncSetAttribute((const void*)gru_persistent,
                      hipFuncAttributeMaxDynamicSharedMemorySize, LDS_BYTES);
  // Arm all four exchange buffers with the sentinel byte pattern.
  hipMemsetAsync(d_ws, 0x7F, WS_INIT_BYTES, stream);
  gru_persistent<<<dim3(NWG), dim3(NT), LDS_BYTES, stream>>>(
      x, h0, Wc, Wu, Wr, bc, bu, br, Wy, by, out, wsu);
}

// Round 4
// 34644.345 us; speedup vs baseline: 1.1100x; 1.1100x over previous
//
#include <hip/hip_runtime.h>
#include <hip/hip_bf16.h>

#define TSTEPS 4096
#define XD 256
#define HD 2048
#define YD 256
#define KD 2304   // XD + HD
#define NWG 256
#define NT 512

// ---- LDS layout (bytes) ----
#define WU_OFF 0
#define WR_OFF (8*KD*2)            // 36864
#define WC_OFF (16*KD*2)           // 73728
#define WY_OFF (24*KD*2)           // 110592
#define V1_OFF (WY_OFF + HD*4)     // 118784  v1 = [x_t | h_{t-1}]
#define V2_OFF (V1_OFF + KD*4)     // 128000  v2 = [x_t | r]
#define RED_OFF (V2_OFF + KD*4)    // 137216  red: u[8], yp[8], bu[8], br[8], bc[8], by
#define LDS_BYTES (RED_OFF + 256)  // 137472

// ---- workspace: double-buffered h and r exchange, sentinel-armed ----
// |h|<=1 and |r|<=1 provably (tanh/sigmoid bounds, h0=0), so 0x7F7F7F7F
// (3.39e38) can never be produced -> safe sentinel, settable via memset(0x7F).
#define HB0_OFF 0
#define HB1_OFF 8192
#define RB0_OFF 16384
#define RB1_OFF 24576
#define WS_INIT_BYTES 32768
#define SENT32 0x7F7F7F7Fu

__device__ __forceinline__ float bflo(unsigned u){ return __uint_as_float(u << 16); }
__device__ __forceinline__ float bfhi(unsigned u){ return __uint_as_float(u & 0xffff0000u); }
__device__ __forceinline__ unsigned short f2bf(float f){
  unsigned b = __float_as_uint(f);
  b += 0x7fffu + ((b >> 16) & 1u);   // RTNE (inputs finite)
  return (unsigned short)(b >> 16);
}
__device__ __forceinline__ float sigmoidf_(float x){ return 1.0f / (1.0f + __expf(-x)); }

__device__ __forceinline__ void gst32f(float* p, float v){
  __hip_atomic_store(p, v, __ATOMIC_RELAXED, __HIP_MEMORY_SCOPE_AGENT);
}

// Coherent coalesced 16B load: sc0 sc1 = bypass L1+L2, serviced at the MALL
// (device coherence point — same visibility as agent-scope atomic loads, but
// coalesces 4 lanes per 128B line instead of per-lane 8B transactions).
__device__ __forceinline__ float4 cohload16(const float4* p){
  float4 r;
  asm volatile("global_load_dwordx4 %0, %1, off sc0 sc1\n\t"
               "s_waitcnt vmcnt(0)"
               : "=v"(r) : "v"(p) : "memory");
  return r;
}

// Poll-gather 2048 floats (8KB) from a sentinel-armed exchange buffer into LDS.
// Each of 512 threads owns 16B: one coalesced poll load per round, with
// s_sleep backoff between failed rounds (R3's uncoalesced full-rate spin
// storm was the regression — this is the fix).
__device__ __forceinline__ void gather2048(const float* gbuf, float* lds, int tid, long* budget){
  const float4* p = (const float4*)gbuf + tid;
  float4 v;
  for (;;) {
    v = cohload16(p);
    unsigned a0 = __float_as_uint(v.x), a1 = __float_as_uint(v.y);
    unsigned a2 = __float_as_uint(v.z), a3 = __float_as_uint(v.w);
    if ((a0 != SENT32) & (a1 != SENT32) & (a2 != SENT32) & (a3 != SENT32)) break;
    if (--(*budget) < 0) break;   // anti-hang: accept stale rather than deadlock
    __builtin_amdgcn_s_sleep(2);  // ~128 cyc backoff; retry paced ~ RTT
  }
  ((float4*)lds)[tid] = v;
}

// Re-arm my 8-float slice (32B) of a consumed exchange buffer with sentinel.
__device__ __forceinline__ void reset_slice(float* gbuf, int col0, int tid){
  if (tid < 2) {
    unsigned long long s = 0x7F7F7F7F7F7F7F7FULL;
    unsigned long long* p = (unsigned long long*)(gbuf + col0) + 2*tid;
    __hip_atomic_store(p,     s, __ATOMIC_RELAXED, __HIP_MEMORY_SCOPE_AGENT);
    __hip_atomic_store(p + 1, s, __ATOMIC_RELAXED, __HIP_MEMORY_SCOPE_AGENT);
  }
}

extern "C" __global__ void __launch_bounds__(NT)
gru_persistent(const float* __restrict__ x,  const float* __restrict__ h0,
               const float* __restrict__ Wc, const float* __restrict__ Wu,
               const float* __restrict__ Wr, const float* __restrict__ bc,
               const float* __restrict__ bu, const float* __restrict__ br,
               const float* __restrict__ Wy, const float* __restrict__ by,
               float* __restrict__ out, unsigned* wsu)
{
  extern __shared__ char smem[];
  unsigned short* wuS = (unsigned short*)(smem + WU_OFF);
  unsigned short* wrS = (unsigned short*)(smem + WR_OFF);
  unsigned short* wcS = (unsigned short*)(smem + WC_OFF);
  float* wyS = (float*)(smem + WY_OFF);
  float* v1  = (float*)(smem + V1_OFF);
  float* v2  = (float*)(smem + V2_OFF);
  float* red = (float*)(smem + RED_OFF);

  float* hb[2] = { (float*)((char*)wsu + HB0_OFF), (float*)((char*)wsu + HB1_OFF) };
  float* rb[2] = { (float*)((char*)wsu + RB0_OFF), (float*)((char*)wsu + RB1_OFF) };

  const int wg = blockIdx.x, tid = threadIdx.x;
  const int col0 = 8 * wg;

  // ---- one-time weight staging: WG j owns gate cols [8j,8j+8), y col j ----
  for (int idx = tid; idx < 8*KD; idx += NT) {
    int c = idx & 7, k = idx >> 3;
    size_t g = (size_t)k * HD + col0 + c;   // W is [KD, 2048] row-major
    wuS[c*KD + k] = f2bf(Wu[g]);
    wrS[c*KD + k] = f2bf(Wr[g]);
    wcS[c*KD + k] = f2bf(Wc[g]);
  }
  for (int k = tid; k < HD; k += NT) wyS[k] = Wy[(size_t)k * YD + wg];
  if (tid < 8) {
    red[16+tid] = bu[col0+tid];
    red[24+tid] = br[col0+tid];
    red[32+tid] = bc[col0+tid];
  }
  if (tid == 0) red[40] = by[wg];
  __syncthreads();

  long budget = 20000000;   // poll-round cap, then bail (no hang)

  for (int t = 0; t < TSTEPS; ++t) {
    // x_t fill (independent; overlaps the h poll) ...
    if (tid < XD/4) {
      float4 xv = ((const float4*)(x + (size_t)t * XD))[tid];
      ((float4*)v1)[tid] = xv;
      ((float4*)v2)[tid] = xv;
    }
    // ... then h_{t-1}: data IS the barrier (poll until non-sentinel)
    if (t == 0) {
      ((float4*)(v1 + XD))[tid] = ((const float4*)h0)[tid];
    } else {
      gather2048(hb[(t+1)&1], v1 + XD, tid, &budget);
    }
    __syncthreads();
    // h_{t-1} complete => every WG published h_{t-1} => every WG consumed
    // r_{t-1} => safe to re-arm my slice of rb[(t-1)&1] (rewritten at t+1;
    // >=2 vmcnt-draining __syncthreads separate this reset from that rewrite).
    if (t) reset_slice(rb[(t+1)&1], col0, tid);

    // ---- phase 1: Lu (half-waves 0-7), Lr (half-waves 8-15); K = 2304 ----
    {
      int hw = tid >> 5, l = tid & 31, c = hw & 7;
      const unsigned short* wcol = ((hw < 8) ? wuS : wrS) + c * KD;
      float4 acc = make_float4(0.f, 0.f, 0.f, 0.f);
      #pragma unroll
      for (int i = 0; i < KD/128; ++i) {       // 18 iters, 4 MACs each
        int k = 4 * (l + 32 * i);
        float4 vv = *(const float4*)(v1 + k);
        uint2  wq = *(const uint2*)(wcol + k);
        acc.x = fmaf(vv.x, bflo(wq.x), acc.x);
        acc.y = fmaf(vv.y, bfhi(wq.x), acc.y);
        acc.z = fmaf(vv.z, bflo(wq.y), acc.z);
        acc.w = fmaf(vv.w, bfhi(wq.y), acc.w);
      }
      float s = (acc.x + acc.y) + (acc.z + acc.w);
      s += __shfl_xor(s, 16); s += __shfl_xor(s, 8); s += __shfl_xor(s, 4);
      s += __shfl_xor(s, 2);  s += __shfl_xor(s, 1);
      if (l == 0) {
        if (hw < 8) red[c] = sigmoidf_(s + red[16+c]);                              // u gate
        else gst32f(rb[t&1] + col0 + c, sigmoidf_(s + red[24+c]) * v1[XD+col0+c]);  // r*h
      }
    }

    // r_t exchange: poll the data directly (fast waves gather while slow
    // waves still compute — no intra-WG sync needed before polling).
    gather2048(rb[t&1], v2 + XD, tid, &budget);
    __syncthreads();
    // r_t complete => every WG finished phase 1 => every WG consumed h_{t-1}
    // => safe to re-arm my slice of hb[(t-1)&1] (rewritten at t+1).
    if (t) reset_slice(hb[(t+1)&1], col0, tid);

    // ---- phase 2: candidate c (wave w -> col w) + y[t-1] partials ----
    {
      int w = tid >> 6, l6 = tid & 63;
      const unsigned short* ccol = wcS + w * KD;
      float4 acc = make_float4(0.f, 0.f, 0.f, 0.f);
      #pragma unroll
      for (int i = 0; i < KD/256; ++i) {       // 9 iters
        int k = 4 * (l6 + 64 * i);
        float4 vv = *(const float4*)(v2 + k);
        uint2  wq = *(const uint2*)(ccol + k);
        acc.x = fmaf(vv.x, bflo(wq.x), acc.x);
        acc.y = fmaf(vv.y, bfhi(wq.x), acc.y);
        acc.z = fmaf(vv.z, bflo(wq.y), acc.z);
        acc.w = fmaf(vv.w, bfhi(wq.y), acc.w);
      }
      float s = (acc.x + acc.y) + (acc.z + acc.w);
      s += __shfl_xor(s, 32); s += __shfl_xor(s, 16); s += __shfl_xor(s, 8);
      s += __shfl_xor(s, 4);  s += __shfl_xor(s, 2);  s += __shfl_xor(s, 1);

      // y[t-1] = h_{t-1} @ Wy[:,wg] : wave w covers k in [256w, 256w+256)
      int k = 256 * w + 4 * l6;
      float4 hv  = *(const float4*)(v1 + XD + k);
      float4 wy4 = *(const float4*)(wyS + k);
      float ys = fmaf(hv.x, wy4.x, fmaf(hv.y, wy4.y, fmaf(hv.z, wy4.z, hv.w * wy4.w)));
      ys += __shfl_xor(ys, 32); ys += __shfl_xor(ys, 16); ys += __shfl_xor(ys, 8);
      ys += __shfl_xor(ys, 4);  ys += __shfl_xor(ys, 2);  ys += __shfl_xor(ys, 1);

      if (l6 == 0) {
        red[8 + w] = ys;
        float cc = tanhf(s + red[32 + w]);
        float u  = red[w];
        float hp = v1[XD + col0 + w];
        gst32f(hb[t&1] + col0 + w, cc * u + hp * (1.0f - u));   // h_t slice
      }
    }
    __syncthreads();
    if (tid == 0 && t > 0) {
      float y = red[8]+red[9]+red[10]+red[11]+red[12]+red[13]+red[14]+red[15] + red[40];
      out[(size_t)(t-1) * YD + wg] = y;   // fire-and-forget; ack hides under next poll
    }
  }

  // ---- epilogue: y[T-1] and h_fin ----
  gather2048(hb[(TSTEPS-1)&1], v1 + XD, tid, &budget);
  __syncthreads();
  {
    int w = tid >> 6, l6 = tid & 63;
    int k = 256 * w + 4 * l6;
    float4 hv  = *(const float4*)(v1 + XD + k);
    float4 wy4 = *(const float4*)(wyS + k);
    float ys = fmaf(hv.x, wy4.x, fmaf(hv.y, wy4.y, fmaf(hv.z, wy4.z, hv.w * wy4.w)));
    ys += __shfl_xor(ys, 32); ys += __shfl_xor(ys, 16); ys += __shfl_xor(ys, 8);
    ys += __shfl_xor(ys, 4);  ys += __shfl_xor(ys, 2);  ys += __shfl_xor(ys, 1);
    if (l6 == 0) red[8 + w] = ys;
  }
  __syncthreads();
  if (tid == 0) {
    float y = red[8]+red[9]+red[10]+red[11]+red[12]+red[13]+red[14]+red[15] + red[40];
    out[(size_t)(TSTEPS-1) * YD + wg] = y;
  }
  if (tid < 8) out[(size_t)TSTEPS * YD + col0 + tid] = v1[XD + col0 + tid];
}

extern "C" void kernel_launch(void* const* d_in, const int* in_sizes, int n_in,
                              void* d_out, int out_size, void* d_ws, size_t ws_size,
                              hipStream_t stream) {
  const float* x  = (const float*)d_in[0];
  const float* h0 = (const float*)d_in[1];
  const float* Wc = (const float*)d_in[2];
  const float* Wu = (const float*)d_in[3];
  const float* Wr = (const float*)d_in[4];
  const float* bc = (const float*)d_in[5];
  const float* bu = (const float*)d_in[6];
  const float* br = (const float*)d_in[7];
  const float* Wy = (const float*)d_in[8];
  const float* by = (const float*)d_in[9];
  float* out = (float*)d_out;
  unsigned* wsu = (unsigned*)d_ws;

  // >64 KB dynamic LDS on gfx950 (160 KB/CU). Idempotent; capture-safe.
  hipFuncSetAttribute((const void*)gru_persistent,
                      hipFuncAttributeMaxDynamicSharedMemorySize, LDS_BYTES);
  // Arm all four exchange buffers with the sentinel byte pattern.
  hipMemsetAsync(d_ws, 0x7F, WS_INIT_BYTES, stream);
  gru_persistent<<<dim3(NWG), dim3(NT), LDS_BYTES, stream>>>(
      x, h0, Wc, Wu, Wr, bc, bu, br, Wy, by, out, wsu);
}

// Round 5
// 27365.271 us; speedup vs baseline: 1.4052x; 1.2660x over previous
//
#include <hip/hip_runtime.h>
#include <hip/hip_bf16.h>

#define TSTEPS 4096
#define XD 256
#define HD 2048
#define YD 256
#define KD 2304   // XD + HD
#define NWG 256
#define NT 512

// ---- LDS layout (bytes) ----
#define WU_OFF 0
#define WR_OFF (8*KD*2)            // 36864
#define WC_OFF (16*KD*2)           // 73728
#define WY_OFF (24*KD*2)           // 110592
#define V1_OFF (WY_OFF + HD*4)     // 118784  v1 = [x_t | h_{t-1}]
#define V2_OFF (V1_OFF + KD*4)     // 128000  v2 = [x_t | r]
#define RED_OFF (V2_OFF + KD*4)    // 137216  red: u[8], yp[8], bu[8], br[8], bc[8], by
#define LDS_BYTES (RED_OFF + 256)  // 137472

// ---- workspace: double-buffered h and r exchange, sentinel-armed ----
// |h|<=1 and |r|<=1 provably (tanh/sigmoid bounds, h0=0), so 0x7F7F7F7F
// (3.39e38) can never be produced -> safe sentinel, settable via memset(0x7F).
#define HB0_OFF 0
#define HB1_OFF 8192
#define RB0_OFF 16384
#define RB1_OFF 24576
#define WS_INIT_BYTES 32768
#define SENT32 0x7F7F7F7Fu

__device__ __forceinline__ float bflo(unsigned u){ return __uint_as_float(u << 16); }
__device__ __forceinline__ float bfhi(unsigned u){ return __uint_as_float(u & 0xffff0000u); }
__device__ __forceinline__ unsigned short f2bf(float f){
  unsigned b = __float_as_uint(f);
  b += 0x7fffu + ((b >> 16) & 1u);   // RTNE (inputs finite)
  return (unsigned short)(b >> 16);
}
__device__ __forceinline__ float sigmoidf_(float x){ return 1.0f / (1.0f + __expf(-x)); }

__device__ __forceinline__ void gst32f(float* p, float v){
  __hip_atomic_store(p, v, __ATOMIC_RELAXED, __HIP_MEMORY_SCOPE_AGENT);
}

// AGENT-scope coalesced 16B load: sc1 ONLY (sc0+sc1 = system scope = bypass
// the LLC -> HBM RTT, which was R4's regression). sc1 alone matches what the
// compiler emits for __hip_atomic_load(...,AGENT) — LLC-serviced, proven
// coherent by R2/R3 — but coalesces 4 lanes per 128B line.
__device__ __forceinline__ float4 cohload16(const float4* p){
  float4 r;
  asm volatile("global_load_dwordx4 %0, %1, off sc1\n\t"
               "s_waitcnt vmcnt(0)"
               : "=v"(r) : "v"(p) : "memory");
  return r;
}

// Poll-gather 2048 floats (8KB) from a sentinel-armed exchange buffer into LDS.
// Each of 512 threads owns 16B: one coalesced agent-scope poll per round,
// s_sleep backoff between failed rounds.
__device__ __forceinline__ void gather2048(const float* gbuf, float* lds, int tid, long* budget){
  const float4* p = (const float4*)gbuf + tid;
  float4 v;
  for (;;) {
    v = cohload16(p);
    unsigned a0 = __float_as_uint(v.x), a1 = __float_as_uint(v.y);
    unsigned a2 = __float_as_uint(v.z), a3 = __float_as_uint(v.w);
    if ((a0 != SENT32) & (a1 != SENT32) & (a2 != SENT32) & (a3 != SENT32)) break;
    if (--(*budget) < 0) break;   // anti-hang: accept stale rather than deadlock
    __builtin_amdgcn_s_sleep(2);  // ~128 cyc backoff; retry paced ~ MALL RTT
  }
  ((float4*)lds)[tid] = v;
}

// Re-arm my 8-float slice (32B) of a consumed exchange buffer with sentinel.
__device__ __forceinline__ void reset_slice(float* gbuf, int col0, int tid){
  if (tid < 2) {
    unsigned long long s = 0x7F7F7F7F7F7F7F7FULL;
    unsigned long long* p = (unsigned long long*)(gbuf + col0) + 2*tid;
    __hip_atomic_store(p,     s, __ATOMIC_RELAXED, __HIP_MEMORY_SCOPE_AGENT);
    __hip_atomic_store(p + 1, s, __ATOMIC_RELAXED, __HIP_MEMORY_SCOPE_AGENT);
  }
}

extern "C" __global__ void __launch_bounds__(NT)
gru_persistent(const float* __restrict__ x,  const float* __restrict__ h0,
               const float* __restrict__ Wc, const float* __restrict__ Wu,
               const float* __restrict__ Wr, const float* __restrict__ bc,
               const float* __restrict__ bu, const float* __restrict__ br,
               const float* __restrict__ Wy, const float* __restrict__ by,
               float* __restrict__ out, unsigned* wsu)
{
  extern __shared__ char smem[];
  unsigned short* wuS = (unsigned short*)(smem + WU_OFF);
  unsigned short* wrS = (unsigned short*)(smem + WR_OFF);
  unsigned short* wcS = (unsigned short*)(smem + WC_OFF);
  float* wyS = (float*)(smem + WY_OFF);
  float* v1  = (float*)(smem + V1_OFF);
  float* v2  = (float*)(smem + V2_OFF);
  float* red = (float*)(smem + RED_OFF);

  float* hb[2] = { (float*)((char*)wsu + HB0_OFF), (float*)((char*)wsu + HB1_OFF) };
  float* rb[2] = { (float*)((char*)wsu + RB0_OFF), (float*)((char*)wsu + RB1_OFF) };

  const int wg = blockIdx.x, tid = threadIdx.x;
  const int col0 = 8 * wg;

  // ---- one-time weight staging: WG j owns gate cols [8j,8j+8), y col j ----
  for (int idx = tid; idx < 8*KD; idx += NT) {
    int c = idx & 7, k = idx >> 3;
    size_t g = (size_t)k * HD + col0 + c;   // W is [KD, 2048] row-major
    wuS[c*KD + k] = f2bf(Wu[g]);
    wrS[c*KD + k] = f2bf(Wr[g]);
    wcS[c*KD + k] = f2bf(Wc[g]);
  }
  for (int k = tid; k < HD; k += NT) wyS[k] = Wy[(size_t)k * YD + wg];
  if (tid < 8) {
    red[16+tid] = bu[col0+tid];
    red[24+tid] = br[col0+tid];
    red[32+tid] = bc[col0+tid];
  }
  if (tid == 0) red[40] = by[wg];
  __syncthreads();

  long budget = 20000000;   // poll-round cap, then bail (no hang)

  for (int t = 0; t < TSTEPS; ++t) {
    // x_t fill (independent; overlaps the h poll) ...
    if (tid < XD/4) {
      float4 xv = ((const float4*)(x + (size_t)t * XD))[tid];
      ((float4*)v1)[tid] = xv;
      ((float4*)v2)[tid] = xv;
    }
    // ... then h_{t-1}: data IS the barrier (poll until non-sentinel)
    if (t == 0) {
      ((float4*)(v1 + XD))[tid] = ((const float4*)h0)[tid];
    } else {
      gather2048(hb[(t+1)&1], v1 + XD, tid, &budget);
    }
    __syncthreads();
    // h_{t-1} complete => every WG published h_{t-1} => every WG consumed
    // r_{t-1} => safe to re-arm my slice of rb[(t-1)&1] (rewritten at t+1;
    // >=2 vmcnt-draining __syncthreads separate this reset from that rewrite).
    if (t) reset_slice(rb[(t+1)&1], col0, tid);

    // ---- phase 1: Lu (half-waves 0-7), Lr (half-waves 8-15); K = 2304 ----
    {
      int hw = tid >> 5, l = tid & 31, c = hw & 7;
      const unsigned short* wcol = ((hw < 8) ? wuS : wrS) + c * KD;
      float4 acc = make_float4(0.f, 0.f, 0.f, 0.f);
      #pragma unroll
      for (int i = 0; i < KD/128; ++i) {       // 18 iters, 4 MACs each
        int k = 4 * (l + 32 * i);
        float4 vv = *(const float4*)(v1 + k);
        uint2  wq = *(const uint2*)(wcol + k);
        acc.x = fmaf(vv.x, bflo(wq.x), acc.x);
        acc.y = fmaf(vv.y, bfhi(wq.x), acc.y);
        acc.z = fmaf(vv.z, bflo(wq.y), acc.z);
        acc.w = fmaf(vv.w, bfhi(wq.y), acc.w);
      }
      float s = (acc.x + acc.y) + (acc.z + acc.w);
      s += __shfl_xor(s, 16); s += __shfl_xor(s, 8); s += __shfl_xor(s, 4);
      s += __shfl_xor(s, 2);  s += __shfl_xor(s, 1);
      if (l == 0) {
        if (hw < 8) red[c] = sigmoidf_(s + red[16+c]);                              // u gate
        else gst32f(rb[t&1] + col0 + c, sigmoidf_(s + red[24+c]) * v1[XD+col0+c]);  // r*h
      }
    }

    // y[t-1] partials: needs only h_{t-1} (in v1) -> compute while the r
    // stores are still in flight, hiding the projection under the exchange.
    {
      int w = tid >> 6, l6 = tid & 63;
      int k = 256 * w + 4 * l6;
      float4 hv  = *(const float4*)(v1 + XD + k);
      float4 wy4 = *(const float4*)(wyS + k);
      float ys = fmaf(hv.x, wy4.x, fmaf(hv.y, wy4.y, fmaf(hv.z, wy4.z, hv.w * wy4.w)));
      ys += __shfl_xor(ys, 32); ys += __shfl_xor(ys, 16); ys += __shfl_xor(ys, 8);
      ys += __shfl_xor(ys, 4);  ys += __shfl_xor(ys, 2);  ys += __shfl_xor(ys, 1);
      if (l6 == 0) red[8 + w] = ys;
    }

    // r_t exchange: poll the data directly (fast waves gather while slow
    // waves still compute — no intra-WG sync needed before polling).
    gather2048(rb[t&1], v2 + XD, tid, &budget);
    __syncthreads();
    // r_t complete => every WG finished phase 1 => every WG consumed h_{t-1}
    // => safe to re-arm my slice of hb[(t-1)&1] (rewritten at t+1).
    if (t) reset_slice(hb[(t+1)&1], col0, tid);

    // ---- phase 2: candidate c (wave w -> col w) ----
    {
      int w = tid >> 6, l6 = tid & 63;
      const unsigned short* ccol = wcS + w * KD;
      float4 acc = make_float4(0.f, 0.f, 0.f, 0.f);
      #pragma unroll
      for (int i = 0; i < KD/256; ++i) {       // 9 iters
        int k = 4 * (l6 + 64 * i);
        float4 vv = *(const float4*)(v2 + k);
        uint2  wq = *(const uint2*)(ccol + k);
        acc.x = fmaf(vv.x, bflo(wq.x), acc.x);
        acc.y = fmaf(vv.y, bfhi(wq.x), acc.y);
        acc.z = fmaf(vv.z, bflo(wq.y), acc.z);
        acc.w = fmaf(vv.w, bfhi(wq.y), acc.w);
      }
      float s = (acc.x + acc.y) + (acc.z + acc.w);
      s += __shfl_xor(s, 32); s += __shfl_xor(s, 16); s += __shfl_xor(s, 8);
      s += __shfl_xor(s, 4);  s += __shfl_xor(s, 2);  s += __shfl_xor(s, 1);

      if (l6 == 0) {
        float cc = tanhf(s + red[32 + w]);
        float u  = red[w];
        float hp = v1[XD + col0 + w];
        gst32f(hb[t&1] + col0 + w, cc * u + hp * (1.0f - u));   // h_t slice
      }
    }
    __syncthreads();
    if (tid == 0 && t > 0) {
      float y = red[8]+red[9]+red[10]+red[11]+red[12]+red[13]+red[14]+red[15] + red[40];
      out[(size_t)(t-1) * YD + wg] = y;   // fire-and-forget; ack hides under next poll
    }
  }

  // ---- epilogue: y[T-1] and h_fin ----
  gather2048(hb[(TSTEPS-1)&1], v1 + XD, tid, &budget);
  __syncthreads();
  {
    int w = tid >> 6, l6 = tid & 63;
    int k = 256 * w + 4 * l6;
    float4 hv  = *(const float4*)(v1 + XD + k);
    float4 wy4 = *(const float4*)(wyS + k);
    float ys = fmaf(hv.x, wy4.x, fmaf(hv.y, wy4.y, fmaf(hv.z, wy4.z, hv.w * wy4.w)));
    ys += __shfl_xor(ys, 32); ys += __shfl_xor(ys, 16); ys += __shfl_xor(ys, 8);
    ys += __shfl_xor(ys, 4);  ys += __shfl_xor(ys, 2);  ys += __shfl_xor(ys, 1);
    if (l6 == 0) red[8 + w] = ys;
  }
  __syncthreads();
  if (tid == 0) {
    float y = red[8]+red[9]+red[10]+red[11]+red[12]+red[13]+red[14]+red[15] + red[40];
    out[(size_t)(TSTEPS-1) * YD + wg] = y;
  }
  if (tid < 8) out[(size_t)TSTEPS * YD + col0 + tid] = v1[XD + col0 + tid];
}

extern "C" void kernel_launch(void* const* d_in, const int* in_sizes, int n_in,
                              void* d_out, int out_size, void* d_ws, size_t ws_size,
                              hipStream_t stream) {
  const float* x  = (const float*)d_in[0];
  const float* h0 = (const float*)d_in[1];
  const float* Wc = (const float*)d_in[2];
  const float* Wu = (const float*)d_in[3];
  const float* Wr = (const float*)d_in[4];
  const float* bc = (const float*)d_in[5];
  const float* bu = (const float*)d_in[6];
  const float* br = (const float*)d_in[7];
  const float* Wy = (const float*)d_in[8];
  const float* by = (const float*)d_in[9];
  float* out = (float*)d_out;
  unsigned* wsu = (unsigned*)d_ws;

  // >64 KB dynamic LDS on gfx950 (160 KB/CU). Idempotent; capture-safe.
  hipFuncSetAttribute((const void*)gru_persistent,
                      hipFuncAttributeMaxDynamicSharedMemorySize, LDS_BYTES);
  // Arm all four exchange buffers with the sentinel byte pattern.
  hipMemsetAsync(d_ws, 0x7F, WS_INIT_BYTES, stream);
  gru_persistent<<<dim3(NWG), dim3(NT), LDS_BYTES, stream>>>(
      x, h0, Wc, Wu, Wr, bc, bu, br, Wy, by, out, wsu);
}